// Round 9
// baseline (502.321 us; speedup 1.0000x reference)
//
#include <hip/hip_runtime.h>
#include <math.h>
#include <stdint.h>

// ---------------------------------------------------------------------------
// MultiHeadAttention, softmax over HEAD axis (dim=1), bf16 MFMA pipeline.
// B=4, S=2048, DIM=1024, H=8, DH=128.
//   cast3/cast4 -> qkv_proj (async cp16, XCD remap) -> fused_attn v12
//   -> gemm_bt<1>.
//   fused_attn v12 = v11 + cross-iteration software pipeline:
//     Pl double-buffered (2 x 64 KB). Per pair of barriers, the barrier-free
//     region contains BOTH step1(t+1) [K loads + 64 QK MFMA + exp -> Pl_next]
//     AND step3(t) [V loads + 64 PV MFMA <- Pl_cur], so load latency hides
//     under MFMA instead of stalling all 8 phase-locked waves. Only step2
//     (merged cross-wave reduce+normalize) stays between barriers.
//     Race audit: between barriers each wave touches only its OWN slices
//     (write next, read cur); cross-wave access only in step2.
// ---------------------------------------------------------------------------

typedef __attribute__((ext_vector_type(8))) __bf16 bf16x8;
typedef __attribute__((ext_vector_type(4))) __bf16 bf16x4;
typedef __attribute__((ext_vector_type(4))) float  f32x4;
typedef __attribute__((ext_vector_type(2))) unsigned int u32x2;

__device__ __forceinline__ f32x4 mfma16(bf16x8 a, bf16x8 b, f32x4 c) {
    return __builtin_amdgcn_mfma_f32_16x16x32_bf16(a, b, c, 0, 0, 0);
}

// async global->LDS, 16B per lane; LDS dest must be wave-uniform-base + lane*16
__device__ __forceinline__ void cp16(void* lds, const void* g) {
    __builtin_amdgcn_global_load_lds(
        (__attribute__((address_space(1))) void*)(void*)(const_cast<void*>(g)),
        (__attribute__((address_space(3))) void*)lds,
        16, 0, 0);
}

// fast exp/rcp: single HW transcendental.
__device__ __forceinline__ float fexp(float x) {
    float r;
    asm("v_exp_f32 %0, %1" : "=v"(r) : "v"(x * 1.44269504088896341f));
    return r;
}
__device__ __forceinline__ float frcp(float x) {
    float r;
    asm("v_rcp_f32 %0, %1" : "=v"(r) : "v"(x));
    return r;
}

// pack two f32 into a dword of two bf16 (RNE via HW cvt)
__device__ __forceinline__ uint32_t pk2(float a, float b) {
    __bf16 x = (__bf16)a, y = (__bf16)b;
    unsigned short xa = __builtin_bit_cast(unsigned short, x);
    unsigned short yb = __builtin_bit_cast(unsigned short, y);
    return (uint32_t)xa | ((uint32_t)yb << 16);
}
__device__ __forceinline__ float bflo(uint32_t d) {
    return __builtin_bit_cast(float, d << 16);
}
__device__ __forceinline__ float bfhi(uint32_t d) {
    return __builtin_bit_cast(float, d & 0xffff0000u);
}

// ---------------------------------------------------------------------------
// 4 weight tensors in one launch
__global__ void cast4_f32_to_bf16(const float* __restrict__ s0, __bf16* __restrict__ d0,
                                  const float* __restrict__ s1, __bf16* __restrict__ d1,
                                  const float* __restrict__ s2, __bf16* __restrict__ d2,
                                  const float* __restrict__ s3, __bf16* __restrict__ d3,
                                  int n4) {
    const float* s = (blockIdx.y == 0) ? s0 : (blockIdx.y == 1) ? s1
                    : (blockIdx.y == 2) ? s2 : s3;
    __bf16* d = (blockIdx.y == 0) ? d0 : (blockIdx.y == 1) ? d1
               : (blockIdx.y == 2) ? d2 : d3;
    int i = blockIdx.x * blockDim.x + threadIdx.x;
    const int stride = gridDim.x * blockDim.x;
    for (; i < n4; i += stride) {
        float4 f = ((const float4*)s)[i];
        bf16x4 o;
        o[0] = (__bf16)f.x; o[1] = (__bf16)f.y; o[2] = (__bf16)f.z; o[3] = (__bf16)f.w;
        ((bf16x4*)d)[i] = o;
    }
}

// Q, K, V activations in one launch (y selects tensor)
__global__ void cast3_f32_to_bf16(const float* __restrict__ s0, __bf16* __restrict__ d0,
                                  const float* __restrict__ s1, __bf16* __restrict__ d1,
                                  const float* __restrict__ s2, __bf16* __restrict__ d2,
                                  int n4) {
    const float* s = (blockIdx.y == 0) ? s0 : (blockIdx.y == 1) ? s1 : s2;
    __bf16* d = (blockIdx.y == 0) ? d0 : (blockIdx.y == 1) ? d1 : d2;
    int i = blockIdx.x * blockDim.x + threadIdx.x;
    const int stride = gridDim.x * blockDim.x;
    for (; i < n4; i += stride) {
        float4 f = ((const float4*)s)[i];
        bf16x4 o;
        o[0] = (__bf16)f.x; o[1] = (__bf16)f.y; o[2] = (__bf16)f.z; o[3] = (__bf16)f.w;
        ((bf16x4*)d)[i] = o;
    }
}

// ---------------------------------------------------------------------------
// C[8192,1024] = A[8192,1024] * Bt[1024,1024]^T   (Bt stored [N,K] row-major)
// MODE 1: f32 out (final WO projection). XCD row-panel remap.
template<int MODE>
__global__ __launch_bounds__(256, 2) void gemm_bt(const __bf16* __restrict__ A,
                                                  const __bf16* __restrict__ Bt,
                                                  void* __restrict__ out,
                                                  float scale)
{
    __shared__ __bf16 As[128 * 32];
    __shared__ __bf16 Bs[128 * 32];
    const int tid  = threadIdx.x;
    const int lane = tid & 63;
    const int u = lane >> 4, v = lane & 15;
    const int w = tid >> 6;
    const int wm = (w >> 1) * 64, wn = (w & 1) * 64;
    const int bid = blockIdx.y * 8 + blockIdx.x;
    const long tM = (long)(bid & 63) * 128;
    const int  tN = (bid >> 6) * 128;

    f32x4 acc[4][4];
#pragma unroll
    for (int i = 0; i < 4; ++i)
#pragma unroll
        for (int j = 0; j < 4; ++j) acc[i][j] = (f32x4){0.f, 0.f, 0.f, 0.f};

    const int c0 = tid, c1 = tid + 256;
    const int ar0 = c0 >> 2, ak0 = (c0 & 3) * 8;
    const int ar1 = c1 >> 2, ak1 = (c1 & 3) * 8;

    const __bf16* Ab = A  + tM * 1024;
    const __bf16* Bb = Bt + (long)tN * 1024;

    for (int k0 = 0; k0 < 1024; k0 += 32) {
        __syncthreads();
        cp16(&As[ar0 * 32 + ak0], Ab + (long)ar0 * 1024 + k0 + ak0);
        cp16(&As[ar1 * 32 + ak1], Ab + (long)ar1 * 1024 + k0 + ak1);
        cp16(&Bs[ar0 * 32 + ak0], Bb + (long)ar0 * 1024 + k0 + ak0);
        cp16(&Bs[ar1 * 32 + ak1], Bb + (long)ar1 * 1024 + k0 + ak1);
        __syncthreads();

        bf16x8 af[4], bfr[4];
#pragma unroll
        for (int i = 0; i < 4; ++i)
            af[i] = *(const bf16x8*)&As[(wm + i * 16 + v) * 32 + u * 8];
#pragma unroll
        for (int j = 0; j < 4; ++j)
            bfr[j] = *(const bf16x8*)&Bs[(wn + j * 16 + v) * 32 + u * 8];
#pragma unroll
        for (int i = 0; i < 4; ++i)
#pragma unroll
            for (int j = 0; j < 4; ++j)
                acc[i][j] = mfma16(af[i], bfr[j], acc[i][j]);
    }

#pragma unroll
    for (int i = 0; i < 4; ++i) {
#pragma unroll
        for (int j = 0; j < 4; ++j) {
            const long row0 = tM + wm + i * 16 + u * 4;
            const int  col  = tN + wn + j * 16 + v;
            if (MODE == 1) {
                float* o = (float*)out;
#pragma unroll
                for (int r = 0; r < 4; ++r)
                    o[(row0 + r) * 1024 + col] = acc[i][j][r];
            } else {
                __bf16* o = (__bf16*)out;
#pragma unroll
                for (int r = 0; r < 4; ++r)
                    o[(row0 + r) * 1024 + col] = (__bf16)(acc[i][j][r] * scale);
            }
        }
    }
}

// ---------------------------------------------------------------------------
// Batched Q/K/V projection, bf16 inputs, async cp16 for BOTH operands
// + XCD row-panel remap.
// z=0: qp=(Xq WQ^T)*qscale; z=1: kp=Xk WK^T; z=2: vt=(Xv WV^T)^T [b,h,dh,s]
__global__ __launch_bounds__(256, 2) void qkv_proj(
    const __bf16* __restrict__ xq, const __bf16* __restrict__ xk,
    const __bf16* __restrict__ xv,
    const __bf16* __restrict__ wq, const __bf16* __restrict__ wk,
    const __bf16* __restrict__ wv,
    __bf16* __restrict__ qp, __bf16* __restrict__ kp, __bf16* __restrict__ vtb,
    float qscale)
{
    __shared__ __bf16 As[128 * 32];
    __shared__ __bf16 Bs[128 * 32];
    const int z = blockIdx.z;
    const __bf16* A  = (z == 0) ? xq : (z == 1) ? xk : xv;
    const __bf16* Bt = (z == 0) ? wq : (z == 1) ? wk : wv;
    __bf16* out      = (z == 0) ? qp : (z == 1) ? kp : vtb;
    const float scale = (z == 0) ? qscale : 1.0f;

    const int tid  = threadIdx.x;
    const int lane = tid & 63;
    const int u = lane >> 4, v = lane & 15;
    const int w = tid >> 6;
    const int wm = (w >> 1) * 64, wn = (w & 1) * 64;
    const int bid = blockIdx.y * 8 + blockIdx.x;
    const long tM = (long)(bid & 63) * 128;
    const int  tN = (bid >> 6) * 128;

    f32x4 acc[4][4];
#pragma unroll
    for (int i = 0; i < 4; ++i)
#pragma unroll
        for (int j = 0; j < 4; ++j) acc[i][j] = (f32x4){0.f, 0.f, 0.f, 0.f};

    const int c0 = tid, c1 = tid + 256;
    const int ar0 = c0 >> 2, ak0 = (c0 & 3) * 8;
    const int ar1 = c1 >> 2, ak1 = (c1 & 3) * 8;

    const __bf16* Ab = A  + tM * 1024;
    const __bf16* Bb = Bt + (long)tN * 1024;

    for (int k0 = 0; k0 < 1024; k0 += 32) {
        __syncthreads();
        cp16(&As[ar0 * 32 + ak0], Ab + (long)ar0 * 1024 + k0 + ak0);
        cp16(&As[ar1 * 32 + ak1], Ab + (long)ar1 * 1024 + k0 + ak1);
        cp16(&Bs[ar0 * 32 + ak0], Bb + (long)ar0 * 1024 + k0 + ak0);
        cp16(&Bs[ar1 * 32 + ak1], Bb + (long)ar1 * 1024 + k0 + ak1);
        __syncthreads();

        bf16x8 af[4], bfr[4];
#pragma unroll
        for (int i = 0; i < 4; ++i)
            af[i] = *(const bf16x8*)&As[(wm + i * 16 + v) * 32 + u * 8];
#pragma unroll
        for (int j = 0; j < 4; ++j)
            bfr[j] = *(const bf16x8*)&Bs[(wn + j * 16 + v) * 32 + u * 8];
#pragma unroll
        for (int i = 0; i < 4; ++i)
#pragma unroll
            for (int j = 0; j < 4; ++j)
                acc[i][j] = mfma16(af[i], bfr[j], acc[i][j]);
    }

#pragma unroll
    for (int i = 0; i < 4; ++i) {
#pragma unroll
        for (int j = 0; j < 4; ++j) {
            const long row0 = tM + wm + i * 16 + u * 4;
            const int  col  = tN + wn + j * 16 + v;
            if (z < 2) {
#pragma unroll
                for (int r = 0; r < 4; ++r)
                    out[(row0 + r) * 1024 + col] = (__bf16)(acc[i][j][r] * scale);
            } else {
                const int bidx = (int)(row0 >> 11);
                const int s    = (int)(row0 & 2047);          // 4-aligned
                const int h = col >> 7, dh = col & 127;
                bf16x4 pkv;
#pragma unroll
                for (int r = 0; r < 4; ++r) pkv[r] = (__bf16)acc[i][j][r];
                *(bf16x4*)&out[((long)(bidx * 8 + h) * 128 + dh) * 2048 + s] = pkv;
            }
        }
    }
}

// ---------------------------------------------------------------------------
// fused_attn v12 helpers (all force-inlined; arrays by reference -> regs)

// step1: QK for one KT=128 tile with 2-deep named-buffer ki prefetch;
// fexp; pack unnormalized bf16(e) into this wave's Pl slice.
__device__ __forceinline__ void step1_qk(
    const __bf16* __restrict__ Kb, const bf16x8 (&qf)[2][4],
    char* PlwBase, int kt, int u, int v, int swz)
{
    bf16x8 kfA[4], kfB[4];
#pragma unroll
    for (int kk = 0; kk < 4; ++kk)
        kfA[kk] = *(const bf16x8*)&Kb[(long)(kt + v) * 1024 + kk * 32 + u * 8];

#pragma unroll
    for (int kp2 = 0; kp2 < 4; ++kp2) {
        const int ki0 = kp2 * 2, ki1 = kp2 * 2 + 1;
#pragma unroll
        for (int kk = 0; kk < 4; ++kk)
            kfB[kk] = *(const bf16x8*)&Kb[(long)(kt + ki1 * 16 + v) * 1024
                                          + kk * 32 + u * 8];
        {
            f32x4 e0 = (f32x4){0.f, 0.f, 0.f, 0.f};
            f32x4 e1 = (f32x4){0.f, 0.f, 0.f, 0.f};
#pragma unroll
            for (int kk = 0; kk < 4; ++kk) {
                e0 = mfma16(kfA[kk], qf[0][kk], e0);
                e1 = mfma16(kfA[kk], qf[1][kk], e1);
            }
#pragma unroll
            for (int r = 0; r < 4; ++r) { e0[r] = fexp(e0[r]); e1[r] = fexp(e1[r]); }
            const int choff = (((ki0 * 2 + (u >> 1)) ^ swz) * 16) + (u & 1) * 8;
            u32x2 w0; w0.x = pk2(e0[0], e0[1]); w0.y = pk2(e0[2], e0[3]);
            u32x2 w1; w1.x = pk2(e1[0], e1[1]); w1.y = pk2(e1[2], e1[3]);
            *(u32x2*)(PlwBase + v * 256 + choff) = w0;
            *(u32x2*)(PlwBase + (16 + v) * 256 + choff) = w1;
        }
        if (ki1 < 7) {
#pragma unroll
            for (int kk = 0; kk < 4; ++kk)
                kfA[kk] = *(const bf16x8*)&Kb[(long)(kt + (ki1 + 1) * 16 + v) * 1024
                                              + kk * 32 + u * 8];
        }
        {
            f32x4 e0 = (f32x4){0.f, 0.f, 0.f, 0.f};
            f32x4 e1 = (f32x4){0.f, 0.f, 0.f, 0.f};
#pragma unroll
            for (int kk = 0; kk < 4; ++kk) {
                e0 = mfma16(kfB[kk], qf[0][kk], e0);
                e1 = mfma16(kfB[kk], qf[1][kk], e1);
            }
#pragma unroll
            for (int r = 0; r < 4; ++r) { e0[r] = fexp(e0[r]); e1[r] = fexp(e1[r]); }
            const int choff = (((ki1 * 2 + (u >> 1)) ^ swz) * 16) + (u & 1) * 8;
            u32x2 w0; w0.x = pk2(e0[0], e0[1]); w0.y = pk2(e0[2], e0[3]);
            u32x2 w1; w1.x = pk2(e1[0], e1[1]); w1.y = pk2(e1[2], e1[3]);
            *(u32x2*)(PlwBase + v * 256 + choff) = w0;
            *(u32x2*)(PlwBase + (16 + v) * 256 + choff) = w1;
        }
    }
}

// step2: merged cross-wave reduce + normalize-writeback for this wave's
// two groups {w, w+8} on the given Pl buffer.
__device__ __forceinline__ void step2_red(char* Pl0, int off_g0, int off_g1)
{
#pragma unroll
    for (int gp = 0; gp < 2; ++gp) {
        const int off = gp ? off_g1 : off_g0;
        u32x2 dw[8];
#pragma unroll
        for (int wp = 0; wp < 8; ++wp)
            dw[wp] = *(const u32x2*)(Pl0 + wp * 8192 + off);
        f32x4 den = (f32x4){0.f, 0.f, 0.f, 0.f};
#pragma unroll
        for (int wp = 0; wp < 8; ++wp) {
            den[0] += bflo(dw[wp].x); den[1] += bfhi(dw[wp].x);
            den[2] += bflo(dw[wp].y); den[3] += bfhi(dw[wp].y);
        }
        f32x4 rv;
#pragma unroll
        for (int r = 0; r < 4; ++r) rv[r] = frcp(den[r]);
#pragma unroll
        for (int wp = 0; wp < 8; ++wp) {
            u32x2 nw;
            nw.x = pk2(bflo(dw[wp].x) * rv[0], bfhi(dw[wp].x) * rv[1]);
            nw.y = pk2(bflo(dw[wp].y) * rv[2], bfhi(dw[wp].y) * rv[3]);
            *(u32x2*)(Pl0 + wp * 8192 + off) = nw;
        }
    }
}

// step3: PV for one KT=128 tile from the given (normalized) Pl buffer.
__device__ __forceinline__ void step3_pv(
    const __bf16* __restrict__ Vb, const char* PlwBase, int kt,
    f32x4 (&ctxa)[8][2], int u, int v, int swz)
{
    __builtin_amdgcn_s_setprio(1);
#pragma unroll
    for (int kc = 0; kc < 4; ++kc) {
        bf16x8 vg[8];
#pragma unroll
        for (int dt = 0; dt < 8; ++dt)
            vg[dt] = *(const bf16x8*)&Vb[(long)(dt * 16 + v) * 2048
                                         + kt + kc * 32 + u * 8];
        bf16x8 pfr0 = *(const bf16x8*)(PlwBase + v * 256
                                       + (((kc * 4 + u) ^ swz) * 16));
        bf16x8 pfr1 = *(const bf16x8*)(PlwBase + (16 + v) * 256
                                       + (((kc * 4 + u) ^ swz) * 16));
#pragma unroll
        for (int dt = 0; dt < 8; ++dt) {
            ctxa[dt][0] = mfma16(vg[dt], pfr0, ctxa[dt][0]);
            ctxa[dt][1] = mfma16(vg[dt], pfr1, ctxa[dt][1]);
        }
    }
    __builtin_amdgcn_s_setprio(0);
}

// ---------------------------------------------------------------------------
// fused_attn v12: QK^T -> head-softmax -> PV, cross-iteration pipelined.
// 256 blocks (XCD bid&7 clusters a batch), 512 threads = 8 waves, wave==head.
// q-tile 32, KT=128, 16 iters, Pl double-buffered (128 KB LDS, 1 block/CU).
// Schedule: [step1(t+1)->next | step3(t)<-cur] barrier-free; bar;
//           step2(next); bar; swap. Only the reduce is phase-locked.
__global__ __launch_bounds__(512, 2) void fused_attn(
    const __bf16* __restrict__ qp, const __bf16* __restrict__ kp,
    const __bf16* __restrict__ vt, __bf16* __restrict__ ctx)
{
    __shared__ __bf16 Pl[2][8][32][128];   // 2 x 64 KB; wave slice 8 KB

    const int tid  = threadIdx.x;
    const int w    = tid >> 6;          // wave == head
    const int lane = tid & 63;
    const int u = lane >> 4, v = lane & 15;

    // XCD (bid&7) serves one batch b; qt spread across XCDs
    const int g0 = blockIdx.x;
    const int xs = g0 & 7, idx = g0 >> 3;
    const int b  = xs >> 1;
    const int qt = idx * 2 + (xs & 1);
    const int q0 = qt * 32;
    const int h  = w;

    const __bf16* Qb = qp + ((long)b * 2048 + q0) * 1024 + h * 128;
    const __bf16* Kb = kp + (long)b * 2048 * 1024 + h * 128;
    const __bf16* Vb = vt + (long)(b * 8 + h) * 128 * 2048;

    // Q fragments resident (32 VGPR)
    bf16x8 qf[2][4];
#pragma unroll
    for (int qj = 0; qj < 2; ++qj)
#pragma unroll
        for (int kk = 0; kk < 4; ++kk)
            qf[qj][kk] = *(const bf16x8*)&Qb[(long)(qj * 16 + v) * 1024 + kk * 32 + u * 8];

    f32x4 ctxa[8][2];
#pragma unroll
    for (int dt = 0; dt < 8; ++dt)
#pragma unroll
        for (int qj = 0; qj < 2; ++qj) ctxa[dt][qj] = (f32x4){0.f, 0.f, 0.f, 0.f};

    char* PlA  = (char*)&Pl[0][w][0][0];
    char* PlB  = (char*)&Pl[1][w][0][0];
    char* Pl0A = (char*)&Pl[0][0][0][0];
    char* Pl0B = (char*)&Pl[1][0][0][0];
    const int swz = v & 15 & 7;

    // merged-reduce slot offsets for this wave's two groups (g = w, w+8)
    const int off_g0 = ((w & 1) * 16 + v) * 256
                     + ((((w >> 1) * 2 + (u >> 1)) ^ swz) * 16) + (u & 1) * 8;
    const int off_g1 = ((w & 1) * 16 + v) * 256
                     + (((((w >> 1) + 4) * 2 + (u >> 1)) ^ swz) * 16) + (u & 1) * 8;

    // prologue: tile 0 through step2 in buffer A
    step1_qk(Kb, qf, PlA, 0, u, v, swz);
    __syncthreads();
    step2_red(Pl0A, off_g0, off_g1);
    __syncthreads();

#pragma unroll 1
    for (int it = 0; it < 16; it += 2) {
        // --- phase A: cur = A(it), next = B(it+1) ---
        if (it + 1 < 16) step1_qk(Kb, qf, PlB, (it + 1) * 128, u, v, swz);
        step3_pv(Vb, PlA, it * 128, ctxa, u, v, swz);
        if (it + 1 < 16) {
            __syncthreads();
            step2_red(Pl0B, off_g0, off_g1);
            __syncthreads();
        }
        // --- phase B: cur = B(it+1), next = A(it+2) ---
        if (it + 2 < 16) step1_qk(Kb, qf, PlA, (it + 2) * 128, u, v, swz);
        if (it + 1 < 16) step3_pv(Vb, PlB, (it + 1) * 128, ctxa, u, v, swz);
        if (it + 2 < 16) {
            __syncthreads();
            step2_red(Pl0A, off_g0, off_g1);
            __syncthreads();
        }
    }

    // ---- epilogue: bf16 ctx, concat layout [b][q][h*128+dh] ----
#pragma unroll
    for (int dt = 0; dt < 8; ++dt)
#pragma unroll
        for (int qj = 0; qj < 2; ++qj) {
            bf16x4 o;
#pragma unroll
            for (int r = 0; r < 4; ++r) o[r] = (__bf16)ctxa[dt][qj][r];
            *(bf16x4*)&ctx[((long)b * 2048 + q0 + qj * 16 + v) * 1024
                           + h * 128 + dt * 16 + u * 4] = o;
        }
}

// ---------------------------------------------------------------------------
extern "C" void kernel_launch(void* const* d_in, const int* in_sizes, int n_in,
                              void* d_out, int out_size, void* d_ws, size_t ws_size,
                              hipStream_t stream)
{
    const float* Q  = (const float*)d_in[0];
    const float* K  = (const float*)d_in[1];
    const float* V  = (const float*)d_in[2];
    const float* WQ = (const float*)d_in[3];
    const float* WK = (const float*)d_in[4];
    const float* WV = (const float*)d_in[5];
    const float* WO = (const float*)d_in[6];

    // workspace (bf16 elems): 4x 1M weights + 7x 8.4M tensors = 125.8 MB
    __bf16* ws = (__bf16*)d_ws;
    __bf16* wq = ws;
    __bf16* wk = wq + 1048576;
    __bf16* wv = wk + 1048576;
    __bf16* wo = wv + 1048576;
    __bf16* xq = wo + 1048576;     // Q cast
    __bf16* xk = xq + 8388608;     // K cast
    __bf16* xv = xk + 8388608;     // V cast
    __bf16* qp = xv + 8388608;
    __bf16* kp = qp + 8388608;
    __bf16* vt = kp + 8388608;
    __bf16* xb = vt + 8388608;     // ctx (bf16)

    const float qscale = 0.08838834764831845f;   // 1/sqrt(128)

    cast4_f32_to_bf16<<<dim3(256, 4), 256, 0, stream>>>(
        WQ, wq, WK, wk, WV, wv, WO, wo, 262144);
    cast3_f32_to_bf16<<<dim3(2048, 3), 256, 0, stream>>>(
        Q, xq, K, xk, V, xv, 2097152);
    qkv_proj<<<dim3(8, 64, 3), 256, 0, stream>>>(
        xq, xk, xv, wq, wk, wv, qp, kp, vt, qscale);

    fused_attn<<<256, 512, 0, stream>>>(qp, kp, vt, xb);

    gemm_bt<1><<<dim3(8, 64), 256, 0, stream>>>(xb, wo, (float*)d_out, 1.0f);
}